// Round 3
// baseline (1054.915 us; speedup 1.0000x reference)
//
#include <hip/hip_runtime.h>

typedef __attribute__((ext_vector_type(8))) short short8;
typedef __attribute__((ext_vector_type(4))) float f32x4;

#define DIM 128
#define RREL 32
#define TM 64

__device__ __forceinline__ ushort f2bf(float f) {
    unsigned u = __builtin_bit_cast(unsigned, f);
    u = (u + 0x7FFFu + ((u >> 16) & 1u)) >> 16;
    return (ushort)u;
}
__device__ __forceinline__ float bf2f(ushort u) {
    return __builtin_bit_cast(float, ((unsigned)u) << 16);
}

// Wt[l][r][n][k] = sum_b coeff[l,r,b] * basis[l,b,k,n]   (bf16, transposed for MFMA B-frag)
__global__ __launch_bounds__(256) void build_w_kernel(const float* __restrict__ coeff,
                                                      const float* __restrict__ basis,
                                                      ushort* __restrict__ Wt) {
    int idx = blockIdx.x * 256 + threadIdx.x;   // [l][r][n][k], k fast
    int k = idx & 127;
    int n = (idx >> 7) & 127;
    int lr = idx >> 14;                          // l*32 + r
    int l = lr >> 5;
    const float* cb = coeff + lr * 8;
    const float* bb = basis + (size_t)l * 8 * 16384 + k * 128 + n;
    float s = 0.f;
#pragma unroll
    for (int b = 0; b < 8; ++b) s += cb[b] * bb[(size_t)b * 16384];
    Wt[idx] = f2bf(s);
}

__global__ __launch_bounds__(256) void tobf16_kernel(const float* __restrict__ in,
                                                     ushort* __restrict__ out, int n8) {
    int i = blockIdx.x * 256 + threadIdx.x;
    if (i >= n8) return;
    const float4* p = (const float4*)in + 2 * (size_t)i;
    float4 a = p[0], b = p[1];
    unsigned w0 = f2bf(a.x) | ((unsigned)f2bf(a.y) << 16);
    unsigned w1 = f2bf(a.z) | ((unsigned)f2bf(a.w) << 16);
    unsigned w2 = f2bf(b.x) | ((unsigned)f2bf(b.y) << 16);
    unsigned w3 = f2bf(b.z) | ((unsigned)f2bf(b.w) << 16);
    ((uint4*)out)[i] = make_uint4(w0, w1, w2, w3);
}

// ---------------- etype-hist + dst-hist in one pass ----------------
__global__ __launch_bounds__(256) void hist2_kernel(const int* __restrict__ et,
                                                    const int* __restrict__ dst, int E,
                                                    int* __restrict__ eh, int* __restrict__ dh) {
    __shared__ int lh[RREL];
    if (threadIdx.x < RREL) lh[threadIdx.x] = 0;
    __syncthreads();
    for (int i = blockIdx.x * 256 + threadIdx.x; i < E; i += gridDim.x * 256) {
        atomicAdd(&lh[et[i]], 1);
        atomicAdd(&dh[dst[i]], 1);
    }
    __syncthreads();
    if (threadIdx.x < RREL) atomicAdd(&eh[threadIdx.x], lh[threadIdx.x]);
}

// etype scan + tile list + dst scan (30000 bins) in one block
__global__ __launch_bounds__(1024) void scan2_kernel(const int* __restrict__ eh,
                                                     const int* __restrict__ dh, int NN, int E,
                                                     int* __restrict__ eoff, int* __restrict__ ecur,
                                                     int2* __restrict__ tiles, int* __restrict__ ntiles,
                                                     int* __restrict__ doff, int* __restrict__ dcur) {
    __shared__ int part[1024];
    __shared__ int eo[RREL + 1], ts[RREL + 1];
    int t = threadIdx.x;
    int chunk = (NN + 1023) >> 10;
    int b0 = t * chunk, b1 = b0 + chunk;
    if (b0 > NN) b0 = NN;
    if (b1 > NN) b1 = NN;
    int s = 0;
    for (int i = b0; i < b1; ++i) s += dh[i];
    part[t] = s;
    __syncthreads();
    for (int off = 1; off < 1024; off <<= 1) {
        int v = (t >= off) ? part[t - off] : 0;
        __syncthreads();
        part[t] += v;
        __syncthreads();
    }
    int run = part[t] - s;   // exclusive prefix
    for (int i = b0; i < b1; ++i) {
        doff[i] = run; dcur[i] = run; run += dh[i];
    }
    if (t == 0) {
        doff[NN] = E;
        int sA = 0, tt = 0;
        for (int r = 0; r < RREL; ++r) {
            eo[r] = sA; ts[r] = tt;
            sA += eh[r]; tt += (eh[r] + TM - 1) / TM;
        }
        eo[RREL] = sA; ts[RREL] = tt;
        *ntiles = tt;
        eoff[RREL] = sA;
    }
    __syncthreads();
    if (t < RREL) {
        eoff[t] = eo[t]; ecur[t] = eo[t];
        int nt = ts[t + 1] - ts[t];
        for (int i = 0; i < nt; ++i) tiles[ts[t] + i] = make_int2(t, eo[t] + i * TM);
    }
}

// pass 1: counting-sort edges into dst order (tie order arbitrary)
__global__ __launch_bounds__(256) void dstsort_kernel(const int* __restrict__ src,
                                                      const int* __restrict__ dst,
                                                      const int* __restrict__ et,
                                                      const float* __restrict__ norm, int E,
                                                      int* __restrict__ dcur,
                                                      int* __restrict__ dsrc, int* __restrict__ det,
                                                      float* __restrict__ dnorm) {
    int i = blockIdx.x * 256 + threadIdx.x;
    if (i >= E) return;
    int p = atomicAdd(&dcur[dst[i]], 1);
    dsrc[p] = src[i];
    det[p] = et[i];
    dnorm[p] = norm[i];
}

// pass 2: etype-sort the dst-sorted stream; opos = dst-sorted index (kept per edge).
// 1024-thread blocks so each per-et chunk grabbed from ecur is a run of dst-near edges
// -> gemm_msg's msg scatter writes land in few ~256KB monotonic windows per tile.
__global__ __launch_bounds__(1024) void etsort_kernel(const int* __restrict__ dsrc,
                                                      const int* __restrict__ det,
                                                      const float* __restrict__ dnorm, int E,
                                                      int* __restrict__ ecur,
                                                      int* __restrict__ src_s,
                                                      float* __restrict__ norm_s,
                                                      int* __restrict__ opos_s) {
    __shared__ int lh[RREL];
    __shared__ int lbase[RREL];
    int i = blockIdx.x * 1024 + threadIdx.x;
    if (threadIdx.x < RREL) lh[threadIdx.x] = 0;
    __syncthreads();
    int r = 0, rank = 0, s = 0;
    float nm = 0.f;
    bool valid = (i < E);
    if (valid) {
        r = det[i]; s = dsrc[i]; nm = dnorm[i];
        rank = atomicAdd(&lh[r], 1);
    }
    __syncthreads();
    if (threadIdx.x < RREL) {
        int c = lh[threadIdx.x];
        if (c > 0) lbase[threadIdx.x] = atomicAdd(&ecur[threadIdx.x], c);
    }
    __syncthreads();
    if (valid) {
        int p = lbase[r] + rank;
        src_s[p] = s;
        norm_s[p] = nm;
        opos_s[p] = i;
    }
}

// One block = one (relation, 64-edge) tile. msg[opos] = bf16((gather(h) @ W_r) * norm), non-atomic.
__global__ __launch_bounds__(256) void gemm_msg_kernel(
    const ushort* __restrict__ hb, const ushort* __restrict__ Wt,
    const int* __restrict__ src_s, const int* __restrict__ opos_s,
    const float* __restrict__ norm_s, const int2* __restrict__ tiles,
    const int* __restrict__ ntiles, const int* __restrict__ offsets,
    ushort* __restrict__ msg) {
    __shared__ char smem[49152];            // A:16K | B:32K ; epilogue C(bf16):16K aliases A
    __shared__ int oposl[TM];
    __shared__ float morml[TM];

    int bx = blockIdx.x;
    if (bx >= *ntiles) return;
    int2 ti = tiles[bx];
    int r = ti.x, row0 = ti.y;
    int rows = offsets[r + 1] - row0;
    if (rows > TM) rows = TM;

    int t = threadIdx.x;
    if (t < rows) { oposl[t] = opos_s[row0 + t]; morml[t] = norm_s[row0 + t]; }

    const int4* Wg = (const int4*)(Wt + (size_t)r * DIM * DIM);
    int4* Bv = (int4*)(smem + 16384);
#pragma unroll
    for (int c = t; c < DIM * DIM / 8; c += 256) {
        int n = c >> 4, ci = c & 15;
        Bv[(n * 16 + ci) ^ (n & 7)] = Wg[c];
    }
    int4* Av = (int4*)smem;
#pragma unroll
    for (int c = t; c < TM * DIM / 8; c += 256) {
        int row = c >> 4, ci = c & 15;
        int e = row0 + (row < rows ? row : rows - 1);
        int s = src_s[e];
        Av[(row * 16 + ci) ^ (row & 7)] = ((const int4*)(hb + (size_t)s * DIM))[ci];
    }
    __syncthreads();

    int w = t >> 6, l = t & 63;
    int wr = w & 1, wc = w >> 1;          // 2x2 wave grid: 32 rows x 64 cols per wave
    int lr16 = l & 15, lhi = l >> 4;

    f32x4 acc[2][4];
#pragma unroll
    for (int m = 0; m < 2; ++m)
#pragma unroll
        for (int n16 = 0; n16 < 4; ++n16) acc[m][n16] = (f32x4)0.f;

    const short8* As = (const short8*)smem;
    const short8* Bs = (const short8*)(smem + 16384);
#pragma unroll
    for (int k4 = 0; k4 < 4; ++k4) {
        int kc = k4 * 4 + lhi;
        int ar0 = wr * 32 + lr16;
        int ar1 = ar0 + 16;
        short8 a0 = As[(ar0 * 16 + kc) ^ (ar0 & 7)];
        short8 a1 = As[(ar1 * 16 + kc) ^ (ar1 & 7)];
#pragma unroll
        for (int n16 = 0; n16 < 4; ++n16) {
            int n = wc * 64 + n16 * 16 + lr16;
            short8 b = Bs[(n * 16 + kc) ^ (n & 7)];
            acc[0][n16] = __builtin_amdgcn_mfma_f32_16x16x32_bf16(a0, b, acc[0][n16], 0, 0, 0);
            acc[1][n16] = __builtin_amdgcn_mfma_f32_16x16x32_bf16(a1, b, acc[1][n16], 0, 0, 0);
        }
    }

    __syncthreads();                          // all waves done reading A/B
    ushort* Cl = (ushort*)smem;               // bf16 C tile, chunk-swizzled like A
#pragma unroll
    for (int m = 0; m < 2; ++m) {
#pragma unroll
        for (int j = 0; j < 4; ++j) {
            int row = wr * 32 + m * 16 + lhi * 4 + j;
            float nm = morml[row];
#pragma unroll
            for (int n16 = 0; n16 < 4; ++n16) {
                int col = wc * 64 + n16 * 16 + lr16;
                Cl[(row * 128 + col) ^ ((row & 7) << 3)] = f2bf(acc[m][n16][j] * nm);
            }
        }
    }
    __syncthreads();
    const int4* Cv = (const int4*)smem;
#pragma unroll
    for (int i = 0; i < 4; ++i) {
        int idx = i * 256 + t;
        int row = idx >> 4, ci = idx & 15;    // 16 int4 per 256B bf16 row
        if (row < rows) {
            int4 v = Cv[(row * 16 + ci) ^ (row & 7)];
            ((int4*)(msg + (size_t)oposl[row] * DIM))[ci] = v;
        }
    }
}

// segment-sum over dst-contiguous msg rows, fused bias+relu, writes f32 and/or bf16.
// 32-lane group per dst; 2 rows in flight (halves), 16B lane loads, shfl_xor(16) combine.
__global__ __launch_bounds__(256) void segsum_kernel(const ushort* __restrict__ msg,
                                                     const int* __restrict__ doff,
                                                     const float* __restrict__ bias,
                                                     float* __restrict__ of32,
                                                     ushort* __restrict__ obf, int NN) {
    int d = blockIdx.x * 8 + (threadIdx.x >> 5);
    if (d >= NN) return;
    int lane = threadIdx.x & 31;
    int half = lane >> 4, ch = lane & 15;
    int s0 = doff[d], s1 = doff[d + 1];
    float a[8];
#pragma unroll
    for (int k = 0; k < 8; ++k) a[k] = 0.f;
    for (int j = s0 + half; j < s1; j += 2) {
        short8 v = *(const short8*)(msg + (size_t)j * DIM + ch * 8);
#pragma unroll
        for (int k = 0; k < 8; ++k) a[k] += bf2f((ushort)v[k]);
    }
#pragma unroll
    for (int k = 0; k < 8; ++k) a[k] += __shfl_xor(a[k], 16);
    if (half == 0) {
        int c = ch * 8;
#pragma unroll
        for (int k = 0; k < 8; ++k) a[k] = fmaxf(a[k] + bias[c + k], 0.f);
        if (of32) {
            float4* o = (float4*)(of32 + (size_t)d * DIM + c);
            o[0] = make_float4(a[0], a[1], a[2], a[3]);
            o[1] = make_float4(a[4], a[5], a[6], a[7]);
        }
        if (obf) {
            uint4 pk;
            pk.x = f2bf(a[0]) | ((unsigned)f2bf(a[1]) << 16);
            pk.y = f2bf(a[2]) | ((unsigned)f2bf(a[3]) << 16);
            pk.z = f2bf(a[4]) | ((unsigned)f2bf(a[5]) << 16);
            pk.w = f2bf(a[6]) | ((unsigned)f2bf(a[7]) << 16);
            *(uint4*)(obf + (size_t)d * DIM + c) = pk;
        }
    }
}

// ---------------- old (fallback) path kernels ----------------
__global__ __launch_bounds__(256) void hist_kernel(const int* __restrict__ et, int E,
                                                   int* __restrict__ hist) {
    __shared__ int lh[RREL];
    if (threadIdx.x < RREL) lh[threadIdx.x] = 0;
    __syncthreads();
    for (int i = blockIdx.x * 256 + threadIdx.x; i < E; i += gridDim.x * 256)
        atomicAdd(&lh[et[i]], 1);
    __syncthreads();
    if (threadIdx.x < RREL) atomicAdd(&hist[threadIdx.x], lh[threadIdx.x]);
}

__global__ void scan_kernel(const int* __restrict__ hist, int* __restrict__ offsets,
                            int* __restrict__ cursor, int2* __restrict__ tiles,
                            int* __restrict__ ntiles) {
    __shared__ int off[RREL + 1];
    __shared__ int ts[RREL + 1];
    if (threadIdx.x == 0) {
        int s = 0, t = 0;
        for (int r = 0; r < RREL; ++r) {
            off[r] = s; ts[r] = t;
            s += hist[r]; t += (hist[r] + TM - 1) / TM;
        }
        off[RREL] = s; ts[RREL] = t;
        *ntiles = t;
    }
    __syncthreads();
    int r = threadIdx.x;
    if (r < RREL) {
        offsets[r] = off[r];
        cursor[r] = off[r];
        int nt = ts[r + 1] - ts[r];
        for (int i = 0; i < nt; ++i) tiles[ts[r] + i] = make_int2(r, off[r] + i * TM);
    }
    if (r == 0) offsets[RREL] = off[RREL];
}

__global__ __launch_bounds__(256) void scatter_kernel(const int* __restrict__ src,
                                                      const int* __restrict__ dst,
                                                      const int* __restrict__ et,
                                                      const float* __restrict__ norm, int E,
                                                      int* __restrict__ cursor,
                                                      int* __restrict__ src_s,
                                                      int* __restrict__ dst_s,
                                                      float* __restrict__ norm_s) {
    __shared__ int lh[RREL];
    __shared__ int lbase[RREL];
    int i = blockIdx.x * 256 + threadIdx.x;
    if (threadIdx.x < RREL) lh[threadIdx.x] = 0;
    __syncthreads();
    int r = 0, rank = 0;
    bool valid = (i < E);
    if (valid) { r = et[i]; rank = atomicAdd(&lh[r], 1); }
    __syncthreads();
    if (threadIdx.x < RREL) {
        int c = lh[threadIdx.x];
        if (c > 0) lbase[threadIdx.x] = atomicAdd(&cursor[threadIdx.x], c);
    }
    __syncthreads();
    if (valid) {
        int p = lbase[r] + rank;
        src_s[p] = src[i]; dst_s[p] = dst[i]; norm_s[p] = norm[i];
    }
}

__global__ __launch_bounds__(256) void gemm_scatter_kernel(
    const ushort* __restrict__ hb, const ushort* __restrict__ Wt,
    const int* __restrict__ src_s, const int* __restrict__ dst_s,
    const float* __restrict__ norm_s, const int2* __restrict__ tiles,
    const int* __restrict__ ntiles, const int* __restrict__ offsets,
    float* __restrict__ agg) {
    __shared__ ushort Alds[TM * DIM];
    __shared__ ushort Blds[DIM * DIM];
    __shared__ int dstl[TM];
    __shared__ float morml[TM];

    int bx = blockIdx.x;
    if (bx >= *ntiles) return;
    int2 ti = tiles[bx];
    int r = ti.x, row0 = ti.y;
    int rows = offsets[r + 1] - row0;
    if (rows > TM) rows = TM;

    int t = threadIdx.x;
    if (t < rows) { dstl[t] = dst_s[row0 + t]; morml[t] = norm_s[row0 + t]; }

    const int4* Wg = (const int4*)(Wt + (size_t)r * DIM * DIM);
    int4* Bv = (int4*)Blds;
#pragma unroll
    for (int c = t; c < DIM * DIM / 8; c += 256) {
        int n = c >> 4, ci = c & 15;
        Bv[(n * 16 + ci) ^ (n & 7)] = Wg[c];
    }
    int4* Av = (int4*)Alds;
#pragma unroll
    for (int c = t; c < TM * DIM / 8; c += 256) {
        int row = c >> 4, ci = c & 15;
        int e = row0 + (row < rows ? row : rows - 1);
        int s = src_s[e];
        Av[(row * 16 + ci) ^ (row & 7)] = ((const int4*)(hb + (size_t)s * DIM))[ci];
    }
    __syncthreads();

    int w = t >> 6, l = t & 63;
    int wr = w & 1, wc = w >> 1;
    int lr16 = l & 15, lhi = l >> 4;

    f32x4 acc[2][4];
#pragma unroll
    for (int m = 0; m < 2; ++m)
#pragma unroll
        for (int n16 = 0; n16 < 4; ++n16) acc[m][n16] = (f32x4)0.f;

    const short8* As = (const short8*)Alds;
    const short8* Bs = (const short8*)Blds;
#pragma unroll
    for (int k4 = 0; k4 < 4; ++k4) {
        int kc = k4 * 4 + lhi;
        int ar0 = wr * 32 + lr16;
        int ar1 = ar0 + 16;
        short8 a0 = As[(ar0 * 16 + kc) ^ (ar0 & 7)];
        short8 a1 = As[(ar1 * 16 + kc) ^ (ar1 & 7)];
#pragma unroll
        for (int n16 = 0; n16 < 4; ++n16) {
            int n = wc * 64 + n16 * 16 + lr16;
            short8 b = Bs[(n * 16 + kc) ^ (n & 7)];
            acc[0][n16] = __builtin_amdgcn_mfma_f32_16x16x32_bf16(a0, b, acc[0][n16], 0, 0, 0);
            acc[1][n16] = __builtin_amdgcn_mfma_f32_16x16x32_bf16(a1, b, acc[1][n16], 0, 0, 0);
        }
    }

#pragma unroll
    for (int m = 0; m < 2; ++m) {
#pragma unroll
        for (int j = 0; j < 4; ++j) {
            int row = wr * 32 + m * 16 + lhi * 4 + j;
            if (row < rows) {
                float nm = morml[row];
                float* ag = agg + (size_t)dstl[row] * DIM;
#pragma unroll
                for (int n16 = 0; n16 < 4; ++n16) {
                    int col = wc * 64 + n16 * 16 + lr16;
                    atomicAdd(ag + col, acc[m][n16][j] * nm);
                }
            }
        }
    }
}

__global__ __launch_bounds__(256) void bias_relu_kernel(const float* __restrict__ agg,
                                                        const float* __restrict__ bias,
                                                        float* __restrict__ of32,
                                                        ushort* __restrict__ obf, int n4) {
    int i = blockIdx.x * 256 + threadIdx.x;
    if (i >= n4) return;
    float4 v = ((const float4*)agg)[i];
    int col = (i << 2) & 127;
    v.x = fmaxf(v.x + bias[col], 0.f);
    v.y = fmaxf(v.y + bias[col + 1], 0.f);
    v.z = fmaxf(v.z + bias[col + 2], 0.f);
    v.w = fmaxf(v.w + bias[col + 3], 0.f);
    if (of32) ((float4*)of32)[i] = v;
    if (obf) {
        unsigned w0 = f2bf(v.x) | ((unsigned)f2bf(v.y) << 16);
        unsigned w1 = f2bf(v.z) | ((unsigned)f2bf(v.w) << 16);
        ((uint2*)obf)[i] = make_uint2(w0, w1);
    }
}

__global__ __launch_bounds__(256) void gather_kernel(const float* __restrict__ p_h,
                                                     const float* __restrict__ n_h,
                                                     const float* __restrict__ w_rel,
                                                     const int* __restrict__ pg_head,
                                                     const int* __restrict__ pg_tail,
                                                     const int* __restrict__ pg_et,
                                                     const int* __restrict__ ng_head,
                                                     const int* __restrict__ ng_tail,
                                                     float* __restrict__ out, int P) {
    long tid = (long)blockIdx.x * 256 + threadIdx.x;
    long total = (long)5 * P * 32;
    if (tid >= total) return;
    int c = (int)(tid & 31);
    long rest = tid >> 5;
    int i = (int)(rest % P);
    int which = (int)(rest / P);
    const float* srcp; int row;
    switch (which) {
        case 0: srcp = p_h;   row = pg_head[i]; break;
        case 1: srcp = p_h;   row = pg_tail[i]; break;
        case 2: srcp = w_rel; row = pg_et[i];   break;
        case 3: srcp = n_h;   row = ng_head[i]; break;
        default: srcp = n_h;  row = ng_tail[i]; break;
    }
    float4 v = ((const float4*)(srcp + (size_t)row * DIM))[c];
    ((float4*)out)[((size_t)which * P + i) * 32 + c] = v;
}

extern "C" void kernel_launch(void* const* d_in, const int* in_sizes, int n_in,
                              void* d_out, int out_size, void* d_ws, size_t ws_size,
                              hipStream_t stream) {
    const float* feats[2] = {(const float*)d_in[0], (const float*)d_in[1]};
    const float* w_relation = (const float*)d_in[2];
    const float* coeff = (const float*)d_in[3];
    const float* basis = (const float*)d_in[4];
    const float* bias = (const float*)d_in[5];
    const int* srcs[2] = {(const int*)d_in[6], (const int*)d_in[10]};
    const int* dsts[2] = {(const int*)d_in[7], (const int*)d_in[11]};
    const int* ets[2] = {(const int*)d_in[8], (const int*)d_in[12]};
    const float* norms[2] = {(const float*)d_in[9], (const float*)d_in[13]};
    const int* pg_head = (const int*)d_in[14];
    const int* pg_tail = (const int*)d_in[15];
    const int* pg_et = (const int*)d_in[16];
    const int* ng_head = (const int*)d_in[17];
    const int* ng_tail = (const int*)d_in[18];

    int E = in_sizes[6];
    int P = in_sizes[14];
    int NN = in_sizes[0] / DIM;
    float* out = (float*)d_out;
    int maxtiles = E / TM + RREL + 1;

    auto al = [](size_t b) { return (b + 255) & ~(size_t)255; };
    size_t need = al((size_t)2 * RREL * DIM * DIM * 2)   // Wt
                + al((size_t)NN * DIM * 2) * 2           // hb, hb2
                + al((size_t)E * 4) * 6                  // src_s, norm_s, opos_s, dsrc, det, dnorm
                + al(RREL * 4) * 2 + al((RREL + 1) * 4) + al(4)
                + al((size_t)maxtiles * 8)
                + al((size_t)NN * 4) * 2 + al((size_t)(NN + 1) * 4)
                + al((size_t)E * DIM * 2);               // msg

    char* w = (char*)d_ws;
    auto alloc = [&](size_t b) { char* p = w; w += (b + 255) & ~(size_t)255; return p; };

    if (need <= ws_size) {
        // ---------------- sorted-message path: no f32 atomics ----------------
        ushort* Wt = (ushort*)alloc((size_t)2 * RREL * DIM * DIM * 2);
        ushort* hb = (ushort*)alloc((size_t)NN * DIM * 2);
        ushort* hb2 = (ushort*)alloc((size_t)NN * DIM * 2);
        int* src_s = (int*)alloc((size_t)E * 4);
        float* norm_s = (float*)alloc((size_t)E * 4);
        int* opos_s = (int*)alloc((size_t)E * 4);
        int* dsrc = (int*)alloc((size_t)E * 4);
        int* det = (int*)alloc((size_t)E * 4);
        float* dnorm = (float*)alloc((size_t)E * 4);
        int* ehist = (int*)alloc(RREL * 4);
        int* ecur = (int*)alloc(RREL * 4);
        int* eoff = (int*)alloc((RREL + 1) * 4);
        int* ntiles = (int*)alloc(4);
        int2* tiles = (int2*)alloc((size_t)maxtiles * 8);
        int* dhist = (int*)alloc((size_t)NN * 4);
        int* dcur = (int*)alloc((size_t)NN * 4);
        int* doff = (int*)alloc((size_t)(NN + 1) * 4);
        ushort* msg = (ushort*)alloc((size_t)E * DIM * 2);

        build_w_kernel<<<(2 * RREL * DIM * DIM) / 256, 256, 0, stream>>>(coeff, basis, Wt);

        for (int g = 0; g < 2; ++g) {
            float* hout = out + (size_t)5 * P * DIM + (size_t)g * NN * DIM;
            tobf16_kernel<<<(NN * DIM / 8 + 255) / 256, 256, 0, stream>>>(feats[g], hb,
                                                                          NN * DIM / 8);
            hipMemsetAsync(ehist, 0, RREL * 4, stream);
            hipMemsetAsync(dhist, 0, (size_t)NN * 4, stream);
            hist2_kernel<<<512, 256, 0, stream>>>(ets[g], dsts[g], E, ehist, dhist);
            scan2_kernel<<<1, 1024, 0, stream>>>(ehist, dhist, NN, E, eoff, ecur, tiles, ntiles,
                                                 doff, dcur);
            dstsort_kernel<<<(E + 255) / 256, 256, 0, stream>>>(srcs[g], dsts[g], ets[g],
                                                                norms[g], E, dcur, dsrc, det,
                                                                dnorm);
            etsort_kernel<<<(E + 1023) / 1024, 1024, 0, stream>>>(dsrc, det, dnorm, E, ecur,
                                                                  src_s, norm_s, opos_s);
            for (int l = 0; l < 2; ++l) {
                gemm_msg_kernel<<<maxtiles, 256, 0, stream>>>(
                    l ? hb2 : hb, Wt + (size_t)l * RREL * DIM * DIM, src_s, opos_s, norm_s,
                    tiles, ntiles, eoff, msg);
                segsum_kernel<<<(NN + 7) / 8, 256, 0, stream>>>(
                    msg, doff, bias + l * DIM, l ? hout : nullptr, l ? nullptr : hb2, NN);
            }
        }
    } else {
        // ---------------- fallback: atomic aggregation path ----------------
        ushort* Wt = (ushort*)alloc((size_t)2 * RREL * DIM * DIM * 2);
        ushort* hb = (ushort*)alloc((size_t)NN * DIM * 2);
        ushort* hb2 = (ushort*)alloc((size_t)NN * DIM * 2);
        float* agg = (float*)alloc((size_t)NN * DIM * 4);
        int* src_s = (int*)alloc((size_t)E * 4);
        int* dst_s = (int*)alloc((size_t)E * 4);
        float* norm_s = (float*)alloc((size_t)E * 4);
        int* hist = (int*)alloc(RREL * 4);
        int* offsets = (int*)alloc((RREL + 1) * 4);
        int* cursor = (int*)alloc(RREL * 4);
        int* ntiles = (int*)alloc(4);
        int2* tiles = (int2*)alloc((size_t)maxtiles * 8);

        build_w_kernel<<<(2 * RREL * DIM * DIM) / 256, 256, 0, stream>>>(coeff, basis, Wt);

        for (int g = 0; g < 2; ++g) {
            float* hout = out + (size_t)5 * P * DIM + (size_t)g * NN * DIM;
            tobf16_kernel<<<(NN * DIM / 8 + 255) / 256, 256, 0, stream>>>(feats[g], hb,
                                                                          NN * DIM / 8);
            hipMemsetAsync(hist, 0, RREL * 4, stream);
            hist_kernel<<<512, 256, 0, stream>>>(ets[g], E, hist);
            scan_kernel<<<1, 64, 0, stream>>>(hist, offsets, cursor, tiles, ntiles);
            scatter_kernel<<<(E + 255) / 256, 256, 0, stream>>>(srcs[g], dsts[g], ets[g],
                                                                norms[g], E, cursor, src_s,
                                                                dst_s, norm_s);
            for (int l = 0; l < 2; ++l) {
                hipMemsetAsync(agg, 0, (size_t)NN * DIM * 4, stream);
                gemm_scatter_kernel<<<maxtiles, 256, 0, stream>>>(
                    l ? hb2 : hb, Wt + (size_t)l * RREL * DIM * DIM, src_s, dst_s, norm_s,
                    tiles, ntiles, offsets, agg);
                bias_relu_kernel<<<(NN * DIM / 4 + 255) / 256, 256, 0, stream>>>(
                    agg, bias + l * DIM, l ? hout : nullptr, l ? nullptr : hb2, NN * DIM / 4);
            }
        }
    }

    const float* p_h = out + (size_t)5 * P * DIM;
    const float* n_h = p_h + (size_t)NN * DIM;
    long gtotal = (long)5 * P * 32;
    gather_kernel<<<(int)((gtotal + 255) / 256), 256, 0, stream>>>(
        p_h, n_h, w_relation, pg_head, pg_tail, pg_et, ng_head, ng_tail, out, P);
}

// Round 4
// 981.823 us; speedup vs baseline: 1.0744x; 1.0744x over previous
//
#include <hip/hip_runtime.h>

typedef __attribute__((ext_vector_type(8))) short short8;
typedef __attribute__((ext_vector_type(4))) float f32x4;

#define DIM 128
#define RREL 32
#define TM 128          // gemm tile rows (edges)

__device__ __forceinline__ ushort f2bf(float f) {
    unsigned u = __builtin_bit_cast(unsigned, f);
    u = (u + 0x7FFFu + ((u >> 16) & 1u)) >> 16;
    return (ushort)u;
}
__device__ __forceinline__ float bf2f(ushort u) {
    return __builtin_bit_cast(float, ((unsigned)u) << 16);
}

// Fused prep: Wt[l][r][n][k] = sum_b coeff*basis (bf16, B-frag layout) AND bf16-convert both feats.
__global__ __launch_bounds__(256) void prep_kernel(const float* __restrict__ coeff,
                                                   const float* __restrict__ basis,
                                                   ushort* __restrict__ Wt,
                                                   const float* __restrict__ f0,
                                                   const float* __restrict__ f1,
                                                   ushort* __restrict__ hb, int nnd,
                                                   int fblocks) {
    int bid = blockIdx.x;
    if (bid < 4096) {                          // W build: 2*32*128*128 elems
        int idx = bid * 256 + threadIdx.x;     // [l][r][n][k], k fast
        int k = idx & 127;
        int n = (idx >> 7) & 127;
        int lr = idx >> 14;
        int l = lr >> 5;
        const float* cb = coeff + lr * 8;
        const float* bb = basis + (size_t)l * 8 * 16384 + k * 128 + n;
        float s = 0.f;
#pragma unroll
        for (int b = 0; b < 8; ++b) s += cb[b] * bb[(size_t)b * 16384];
        Wt[idx] = f2bf(s);
    } else {                                   // feats -> bf16, both graphs
        int fb = bid - 4096;
        int g = fb / fblocks;
        int i = (fb - g * fblocks) * 256 + threadIdx.x;
        int n8 = nnd / 8;
        if (i >= n8) return;
        const float* in = g ? f1 : f0;
        ushort* out = hb + (size_t)g * nnd;
        const float4* p = (const float4*)in + 2 * (size_t)i;
        float4 a = p[0], b = p[1];
        unsigned w0 = f2bf(a.x) | ((unsigned)f2bf(a.y) << 16);
        unsigned w1 = f2bf(a.z) | ((unsigned)f2bf(a.w) << 16);
        unsigned w2 = f2bf(b.x) | ((unsigned)f2bf(b.y) << 16);
        unsigned w3 = f2bf(b.z) | ((unsigned)f2bf(b.w) << 16);
        ((uint4*)out)[i] = make_uint4(w0, w1, w2, w3);
    }
}

__global__ __launch_bounds__(256) void hist2_kernel(const int* __restrict__ et,
                                                    const int* __restrict__ dst, int E,
                                                    int* __restrict__ eh, int* __restrict__ dh) {
    __shared__ int lh[RREL];
    if (threadIdx.x < RREL) lh[threadIdx.x] = 0;
    __syncthreads();
    for (int i = blockIdx.x * 256 + threadIdx.x; i < E; i += gridDim.x * 256) {
        atomicAdd(&lh[et[i]], 1);
        atomicAdd(&dh[dst[i]], 1);
    }
    __syncthreads();
    if (threadIdx.x < RREL) atomicAdd(&eh[threadIdx.x], lh[threadIdx.x]);
}

// etype scan + tile list (TM-row tiles) + dst scan in one block
__global__ __launch_bounds__(1024) void scan2_kernel(const int* __restrict__ eh,
                                                     const int* __restrict__ dh, int NN, int E,
                                                     int* __restrict__ eoff, int* __restrict__ ecur,
                                                     int2* __restrict__ tiles, int* __restrict__ ntiles,
                                                     int* __restrict__ doff, int* __restrict__ dcur) {
    __shared__ int part[1024];
    __shared__ int eo[RREL + 1], ts[RREL + 1];
    int t = threadIdx.x;
    int chunk = (NN + 1023) >> 10;
    int b0 = t * chunk, b1 = b0 + chunk;
    if (b0 > NN) b0 = NN;
    if (b1 > NN) b1 = NN;
    int s = 0;
    for (int i = b0; i < b1; ++i) s += dh[i];
    part[t] = s;
    __syncthreads();
    for (int off = 1; off < 1024; off <<= 1) {
        int v = (t >= off) ? part[t - off] : 0;
        __syncthreads();
        part[t] += v;
        __syncthreads();
    }
    int run = part[t] - s;
    for (int i = b0; i < b1; ++i) {
        doff[i] = run; dcur[i] = run; run += dh[i];
    }
    if (t == 0) {
        doff[NN] = E;
        int sA = 0, tt = 0;
        for (int r = 0; r < RREL; ++r) {
            eo[r] = sA; ts[r] = tt;
            sA += eh[r]; tt += (eh[r] + TM - 1) / TM;
        }
        eo[RREL] = sA; ts[RREL] = tt;
        *ntiles = tt;
        eoff[RREL] = sA;
    }
    __syncthreads();
    if (t < RREL) {
        eoff[t] = eo[t]; ecur[t] = eo[t];
        int nt = ts[t + 1] - ts[t];
        for (int i = 0; i < nt; ++i) tiles[ts[t] + i] = make_int2(t, eo[t] + i * TM);
    }
}

// pass 1: counting-sort edges into dst order
__global__ __launch_bounds__(256) void dstsort_kernel(const int* __restrict__ src,
                                                      const int* __restrict__ dst,
                                                      const int* __restrict__ et,
                                                      const float* __restrict__ norm, int E,
                                                      int* __restrict__ dcur,
                                                      int* __restrict__ dsrc, int* __restrict__ det,
                                                      float* __restrict__ dnorm) {
    int i = blockIdx.x * 256 + threadIdx.x;
    if (i >= E) return;
    int p = atomicAdd(&dcur[dst[i]], 1);
    dsrc[p] = src[i];
    det[p] = et[i];
    dnorm[p] = norm[i];
}

// pass 2: etype-sort the dst-sorted stream; opos = dst-sorted index
__global__ __launch_bounds__(1024) void etsort_kernel(const int* __restrict__ dsrc,
                                                      const int* __restrict__ det,
                                                      const float* __restrict__ dnorm, int E,
                                                      int* __restrict__ ecur,
                                                      int* __restrict__ src_s,
                                                      float* __restrict__ norm_s,
                                                      int* __restrict__ opos_s) {
    __shared__ int lh[RREL];
    __shared__ int lbase[RREL];
    int i = blockIdx.x * 1024 + threadIdx.x;
    if (threadIdx.x < RREL) lh[threadIdx.x] = 0;
    __syncthreads();
    int r = 0, rank = 0, s = 0;
    float nm = 0.f;
    bool valid = (i < E);
    if (valid) {
        r = det[i]; s = dsrc[i]; nm = dnorm[i];
        rank = atomicAdd(&lh[r], 1);
    }
    __syncthreads();
    if (threadIdx.x < RREL) {
        int c = lh[threadIdx.x];
        if (c > 0) lbase[threadIdx.x] = atomicAdd(&ecur[threadIdx.x], c);
    }
    __syncthreads();
    if (valid) {
        int p = lbase[r] + rank;
        src_s[p] = s;
        norm_s[p] = nm;
        opos_s[p] = i;
    }
}

// One block = one (relation, 128-edge) tile, 512 threads (8 waves, 2x4 wave grid).
// msg[opos] = bf16((gather(h) @ W_r) * norm), non-atomic coalesced row writes.
__global__ __launch_bounds__(512) void gemm_msg_kernel(
    const ushort* __restrict__ hb, const ushort* __restrict__ Wt,
    const int* __restrict__ src_s, const int* __restrict__ opos_s,
    const float* __restrict__ norm_s, const int2* __restrict__ tiles,
    const int* __restrict__ ntiles, const int* __restrict__ offsets,
    ushort* __restrict__ msg) {
    __shared__ char smem[65536];            // A:32K | B:32K ; epilogue C(bf16, 32K) aliases A
    __shared__ int oposl[TM];
    __shared__ float morml[TM];

    int bx = blockIdx.x;
    if (bx >= *ntiles) return;
    int2 ti = tiles[bx];
    int r = ti.x, row0 = ti.y;
    int rows = offsets[r + 1] - row0;
    if (rows > TM) rows = TM;

    int t = threadIdx.x;
    if (t < rows) { oposl[t] = opos_s[row0 + t]; morml[t] = norm_s[row0 + t]; }

    const int4* Wg = (const int4*)(Wt + (size_t)r * DIM * DIM);
    int4* Bv = (int4*)(smem + 32768);
#pragma unroll
    for (int c = t; c < DIM * DIM / 8; c += 512) {   // 2048 int4
        int n = c >> 4, ci = c & 15;
        Bv[(n * 16 + ci) ^ (n & 7)] = Wg[c];
    }
    int4* Av = (int4*)smem;
#pragma unroll
    for (int c = t; c < TM * DIM / 8; c += 512) {    // 2048 int4
        int row = c >> 4, ci = c & 15;
        int e = row0 + (row < rows ? row : rows - 1);
        int s = src_s[e];
        Av[(row * 16 + ci) ^ (row & 7)] = ((const int4*)(hb + (size_t)s * DIM))[ci];
    }
    __syncthreads();

    int w = t >> 6, l = t & 63;
    int wr = w >> 2, wc = w & 3;          // 2x4 wave grid: 64 rows x 32 cols per wave
    int lr16 = l & 15, lhi = l >> 4;

    f32x4 acc[4][2];
#pragma unroll
    for (int m = 0; m < 4; ++m)
#pragma unroll
        for (int n16 = 0; n16 < 2; ++n16) acc[m][n16] = (f32x4)0.f;

    const short8* As = (const short8*)smem;
    const short8* Bs = (const short8*)(smem + 32768);
#pragma unroll
    for (int k4 = 0; k4 < 4; ++k4) {
        int kc = k4 * 4 + lhi;
        short8 a[4];
#pragma unroll
        for (int m = 0; m < 4; ++m) {
            int ar = wr * 64 + m * 16 + lr16;
            a[m] = As[(ar * 16 + kc) ^ (ar & 7)];
        }
#pragma unroll
        for (int n16 = 0; n16 < 2; ++n16) {
            int n = wc * 32 + n16 * 16 + lr16;
            short8 b = Bs[(n * 16 + kc) ^ (n & 7)];
#pragma unroll
            for (int m = 0; m < 4; ++m)
                acc[m][n16] = __builtin_amdgcn_mfma_f32_16x16x32_bf16(a[m], b, acc[m][n16], 0, 0, 0);
        }
    }

    __syncthreads();                          // all waves done reading A/B
    ushort* Cl = (ushort*)smem;               // bf16 C tile aliasing A, chunk-swizzled
#pragma unroll
    for (int m = 0; m < 4; ++m) {
#pragma unroll
        for (int j = 0; j < 4; ++j) {
            int row = wr * 64 + m * 16 + lhi * 4 + j;
            float nm = morml[row];
#pragma unroll
            for (int n16 = 0; n16 < 2; ++n16) {
                int col = wc * 32 + n16 * 16 + lr16;
                Cl[(row * 128 + col) ^ ((row & 7) << 3)] = f2bf(acc[m][n16][j] * nm);
            }
        }
    }
    __syncthreads();
    const int4* Cv = (const int4*)smem;
#pragma unroll
    for (int i = 0; i < 4; ++i) {
        int idx = i * 512 + t;
        int row = idx >> 4, ci = idx & 15;
        if (row < rows) {
            int4 v = Cv[(row * 16 + ci) ^ (row & 7)];
            ((int4*)(msg + (size_t)oposl[row] * DIM))[ci] = v;
        }
    }
}

// segment-sum: one 64-lane wave per dst (4 rows in flight), fused bias+relu.
__global__ __launch_bounds__(256) void segsum_kernel(const ushort* __restrict__ msg,
                                                     const int* __restrict__ doff,
                                                     const float* __restrict__ bias,
                                                     float* __restrict__ of32,
                                                     ushort* __restrict__ obf, int NN) {
    int d = blockIdx.x * 4 + (threadIdx.x >> 6);
    if (d >= NN) return;
    int l = threadIdx.x & 63;
    int rowoff = l >> 4, ch = l & 15;
    int s0 = doff[d], s1 = doff[d + 1];
    float a[8];
#pragma unroll
    for (int k = 0; k < 8; ++k) a[k] = 0.f;
    for (int j = s0 + rowoff; j < s1; j += 4) {
        short8 v = *(const short8*)(msg + (size_t)j * DIM + ch * 8);
#pragma unroll
        for (int k = 0; k < 8; ++k) a[k] += bf2f((ushort)v[k]);
    }
#pragma unroll
    for (int k = 0; k < 8; ++k) {
        a[k] += __shfl_xor(a[k], 16);
        a[k] += __shfl_xor(a[k], 32);
    }
    if (rowoff == 0) {                     // lanes 0..15 hold the sums
        int c = ch * 8;
#pragma unroll
        for (int k = 0; k < 8; ++k) a[k] = fmaxf(a[k] + bias[c + k], 0.f);
        if (of32) {
            float4* o = (float4*)(of32 + (size_t)d * DIM + c);
            o[0] = make_float4(a[0], a[1], a[2], a[3]);
            o[1] = make_float4(a[4], a[5], a[6], a[7]);
        }
        if (obf) {
            uint4 pk;
            pk.x = f2bf(a[0]) | ((unsigned)f2bf(a[1]) << 16);
            pk.y = f2bf(a[2]) | ((unsigned)f2bf(a[3]) << 16);
            pk.z = f2bf(a[4]) | ((unsigned)f2bf(a[5]) << 16);
            pk.w = f2bf(a[6]) | ((unsigned)f2bf(a[7]) << 16);
            *(uint4*)(obf + (size_t)d * DIM + c) = pk;
        }
    }
}

__global__ __launch_bounds__(256) void gather_kernel(const float* __restrict__ p_h,
                                                     const float* __restrict__ n_h,
                                                     const float* __restrict__ w_rel,
                                                     const int* __restrict__ pg_head,
                                                     const int* __restrict__ pg_tail,
                                                     const int* __restrict__ pg_et,
                                                     const int* __restrict__ ng_head,
                                                     const int* __restrict__ ng_tail,
                                                     float* __restrict__ out, int P) {
    long tid = (long)blockIdx.x * 256 + threadIdx.x;
    long total = (long)5 * P * 32;
    if (tid >= total) return;
    int c = (int)(tid & 31);
    long rest = tid >> 5;
    int i = (int)(rest % P);
    int which = (int)(rest / P);
    const float* srcp; int row;
    switch (which) {
        case 0: srcp = p_h;   row = pg_head[i]; break;
        case 1: srcp = p_h;   row = pg_tail[i]; break;
        case 2: srcp = w_rel; row = pg_et[i];   break;
        case 3: srcp = n_h;   row = ng_head[i]; break;
        default: srcp = n_h;  row = ng_tail[i]; break;
    }
    float4 v = ((const float4*)(srcp + (size_t)row * DIM))[c];
    ((float4*)out)[((size_t)which * P + i) * 32 + c] = v;
}

// ---------------- fallback (atomic) path kernels ----------------
__global__ __launch_bounds__(256) void hist_kernel(const int* __restrict__ et, int E,
                                                   int* __restrict__ hist) {
    __shared__ int lh[RREL];
    if (threadIdx.x < RREL) lh[threadIdx.x] = 0;
    __syncthreads();
    for (int i = blockIdx.x * 256 + threadIdx.x; i < E; i += gridDim.x * 256)
        atomicAdd(&lh[et[i]], 1);
    __syncthreads();
    if (threadIdx.x < RREL) atomicAdd(&hist[threadIdx.x], lh[threadIdx.x]);
}

__global__ void scan_kernel(const int* __restrict__ hist, int* __restrict__ offsets,
                            int* __restrict__ cursor, int2* __restrict__ tiles,
                            int* __restrict__ ntiles) {
    __shared__ int off[RREL + 1];
    __shared__ int ts[RREL + 1];
    if (threadIdx.x == 0) {
        int s = 0, t = 0;
        for (int r = 0; r < RREL; ++r) {
            off[r] = s; ts[r] = t;
            s += hist[r]; t += (hist[r] + 63) / 64;
        }
        off[RREL] = s; ts[RREL] = t;
        *ntiles = t;
    }
    __syncthreads();
    int r = threadIdx.x;
    if (r < RREL) {
        offsets[r] = off[r];
        cursor[r] = off[r];
        int nt = ts[r + 1] - ts[r];
        for (int i = 0; i < nt; ++i) tiles[ts[r] + i] = make_int2(r, off[r] + i * 64);
    }
    if (r == 0) offsets[RREL] = off[RREL];
}

__global__ __launch_bounds__(256) void scatter_kernel(const int* __restrict__ src,
                                                      const int* __restrict__ dst,
                                                      const int* __restrict__ et,
                                                      const float* __restrict__ norm, int E,
                                                      int* __restrict__ cursor,
                                                      int* __restrict__ src_s,
                                                      int* __restrict__ dst_s,
                                                      float* __restrict__ norm_s) {
    __shared__ int lh[RREL];
    __shared__ int lbase[RREL];
    int i = blockIdx.x * 256 + threadIdx.x;
    if (threadIdx.x < RREL) lh[threadIdx.x] = 0;
    __syncthreads();
    int r = 0, rank = 0;
    bool valid = (i < E);
    if (valid) { r = et[i]; rank = atomicAdd(&lh[r], 1); }
    __syncthreads();
    if (threadIdx.x < RREL) {
        int c = lh[threadIdx.x];
        if (c > 0) lbase[threadIdx.x] = atomicAdd(&cursor[threadIdx.x], c);
    }
    __syncthreads();
    if (valid) {
        int p = lbase[r] + rank;
        src_s[p] = src[i]; dst_s[p] = dst[i]; norm_s[p] = norm[i];
    }
}

__global__ __launch_bounds__(256) void gemm_scatter_kernel(
    const ushort* __restrict__ hb, const ushort* __restrict__ Wt,
    const int* __restrict__ src_s, const int* __restrict__ dst_s,
    const float* __restrict__ norm_s, const int2* __restrict__ tiles,
    const int* __restrict__ ntiles, const int* __restrict__ offsets,
    float* __restrict__ agg) {
    __shared__ ushort Alds[64 * DIM];
    __shared__ ushort Blds[DIM * DIM];
    __shared__ int dstl[64];
    __shared__ float morml[64];

    int bx = blockIdx.x;
    if (bx >= *ntiles) return;
    int2 ti = tiles[bx];
    int r = ti.x, row0 = ti.y;
    int rows = offsets[r + 1] - row0;
    if (rows > 64) rows = 64;

    int t = threadIdx.x;
    if (t < rows) { dstl[t] = dst_s[row0 + t]; morml[t] = norm_s[row0 + t]; }

    const int4* Wg = (const int4*)(Wt + (size_t)r * DIM * DIM);
    int4* Bv = (int4*)Blds;
#pragma unroll
    for (int c = t; c < DIM * DIM / 8; c += 256) {
        int n = c >> 4, ci = c & 15;
        Bv[(n * 16 + ci) ^ (n & 7)] = Wg[c];
    }
    int4* Av = (int4*)Alds;
#pragma unroll
    for (int c = t; c < 64 * DIM / 8; c += 256) {
        int row = c >> 4, ci = c & 15;
        int e = row0 + (row < rows ? row : rows - 1);
        int s = src_s[e];
        Av[(row * 16 + ci) ^ (row & 7)] = ((const int4*)(hb + (size_t)s * DIM))[ci];
    }
    __syncthreads();

    int w = t >> 6, l = t & 63;
    int wr = w & 1, wc = w >> 1;
    int lr16 = l & 15, lhi = l >> 4;

    f32x4 acc[2][4];
#pragma unroll
    for (int m = 0; m < 2; ++m)
#pragma unroll
        for (int n16 = 0; n16 < 4; ++n16) acc[m][n16] = (f32x4)0.f;

    const short8* As = (const short8*)Alds;
    const short8* Bs = (const short8*)Blds;
#pragma unroll
    for (int k4 = 0; k4 < 4; ++k4) {
        int kc = k4 * 4 + lhi;
        int ar0 = wr * 32 + lr16;
        int ar1 = ar0 + 16;
        short8 a0 = As[(ar0 * 16 + kc) ^ (ar0 & 7)];
        short8 a1 = As[(ar1 * 16 + kc) ^ (ar1 & 7)];
#pragma unroll
        for (int n16 = 0; n16 < 4; ++n16) {
            int n = wc * 64 + n16 * 16 + lr16;
            short8 b = Bs[(n * 16 + kc) ^ (n & 7)];
            acc[0][n16] = __builtin_amdgcn_mfma_f32_16x16x32_bf16(a0, b, acc[0][n16], 0, 0, 0);
            acc[1][n16] = __builtin_amdgcn_mfma_f32_16x16x32_bf16(a1, b, acc[1][n16], 0, 0, 0);
        }
    }

#pragma unroll
    for (int m = 0; m < 2; ++m) {
#pragma unroll
        for (int j = 0; j < 4; ++j) {
            int row = wr * 32 + m * 16 + lhi * 4 + j;
            if (row < rows) {
                float nm = morml[row];
                float* ag = agg + (size_t)dstl[row] * DIM;
#pragma unroll
                for (int n16 = 0; n16 < 4; ++n16) {
                    int col = wc * 64 + n16 * 16 + lr16;
                    atomicAdd(ag + col, acc[m][n16][j] * nm);
                }
            }
        }
    }
}

__global__ __launch_bounds__(256) void bias_relu_kernel(const float* __restrict__ agg,
                                                        const float* __restrict__ bias,
                                                        float* __restrict__ of32,
                                                        ushort* __restrict__ obf, int n4) {
    int i = blockIdx.x * 256 + threadIdx.x;
    if (i >= n4) return;
    float4 v = ((const float4*)agg)[i];
    int col = (i << 2) & 127;
    v.x = fmaxf(v.x + bias[col], 0.f);
    v.y = fmaxf(v.y + bias[col + 1], 0.f);
    v.z = fmaxf(v.z + bias[col + 2], 0.f);
    v.w = fmaxf(v.w + bias[col + 3], 0.f);
    if (of32) ((float4*)of32)[i] = v;
    if (obf) {
        unsigned w0 = f2bf(v.x) | ((unsigned)f2bf(v.y) << 16);
        unsigned w1 = f2bf(v.z) | ((unsigned)f2bf(v.w) << 16);
        ((uint2*)obf)[i] = make_uint2(w0, w1);
    }
}

extern "C" void kernel_launch(void* const* d_in, const int* in_sizes, int n_in,
                              void* d_out, int out_size, void* d_ws, size_t ws_size,
                              hipStream_t stream) {
    const float* feats[2] = {(const float*)d_in[0], (const float*)d_in[1]};
    const float* w_relation = (const float*)d_in[2];
    const float* coeff = (const float*)d_in[3];
    const float* basis = (const float*)d_in[4];
    const float* bias = (const float*)d_in[5];
    const int* srcs[2] = {(const int*)d_in[6], (const int*)d_in[10]};
    const int* dsts[2] = {(const int*)d_in[7], (const int*)d_in[11]};
    const int* ets[2] = {(const int*)d_in[8], (const int*)d_in[12]};
    const float* norms[2] = {(const float*)d_in[9], (const float*)d_in[13]};
    const int* pg_head = (const int*)d_in[14];
    const int* pg_tail = (const int*)d_in[15];
    const int* pg_et = (const int*)d_in[16];
    const int* ng_head = (const int*)d_in[17];
    const int* ng_tail = (const int*)d_in[18];

    int E = in_sizes[6];
    int P = in_sizes[14];
    int NN = in_sizes[0] / DIM;
    int nnd = NN * DIM;
    float* out = (float*)d_out;
    int maxtiles = E / TM + RREL + 1;

    auto al = [](size_t b) { return (b + 255) & ~(size_t)255; };
    size_t need = al((size_t)2 * RREL * DIM * DIM * 2)   // Wt
                + al((size_t)2 * nnd * 2)                // hb (both graphs)
                + al((size_t)nnd * 2)                    // hb2 (shared)
                + al((size_t)E * 4) * 6                  // src_s, norm_s, opos_s, dsrc, det, dnorm
                + al(RREL * 4) * 2 + al((RREL + 1) * 4) + al(4)
                + al((size_t)maxtiles * 8)
                + al((size_t)NN * 4) * 2 + al((size_t)(NN + 1) * 4)
                + al((size_t)E * DIM * 2);               // msg

    char* w = (char*)d_ws;
    auto alloc = [&](size_t b) { char* p = w; w += (b + 255) & ~(size_t)255; return p; };

    if (need <= ws_size) {
        ushort* Wt = (ushort*)alloc((size_t)2 * RREL * DIM * DIM * 2);
        ushort* hb = (ushort*)alloc((size_t)2 * nnd * 2);
        ushort* hb2 = (ushort*)alloc((size_t)nnd * 2);
        int* src_s = (int*)alloc((size_t)E * 4);
        float* norm_s = (float*)alloc((size_t)E * 4);
        int* opos_s = (int*)alloc((size_t)E * 4);
        int* dsrc = (int*)alloc((size_t)E * 4);
        int* det = (int*)alloc((size_t)E * 4);
        float* dnorm = (float*)alloc((size_t)E * 4);
        int* ehist = (int*)alloc(RREL * 4);        // ehist..dhist cleared with ONE memset
        int* ecur = (int*)alloc(RREL * 4);
        int* eoff = (int*)alloc((RREL + 1) * 4);
        int* ntiles = (int*)alloc(4);
        int2* tiles = (int2*)alloc((size_t)maxtiles * 8);
        int* dhist = (int*)alloc((size_t)NN * 4);
        int* dcur = (int*)alloc((size_t)NN * 4);
        int* doff = (int*)alloc((size_t)(NN + 1) * 4);
        ushort* msg = (ushort*)alloc((size_t)E * DIM * 2);

        size_t clr_bytes = ((char*)dhist + (size_t)NN * 4) - (char*)ehist;

        int fblocks = (nnd / 8 + 255) / 256;
        prep_kernel<<<4096 + 2 * fblocks, 256, 0, stream>>>(coeff, basis, Wt, feats[0], feats[1],
                                                            hb, nnd, fblocks);

        for (int g = 0; g < 2; ++g) {
            float* hout = out + (size_t)5 * P * DIM + (size_t)g * nnd;
            hipMemsetAsync(ehist, 0, clr_bytes, stream);
            hist2_kernel<<<512, 256, 0, stream>>>(ets[g], dsts[g], E, ehist, dhist);
            scan2_kernel<<<1, 1024, 0, stream>>>(ehist, dhist, NN, E, eoff, ecur, tiles, ntiles,
                                                 doff, dcur);
            dstsort_kernel<<<(E + 255) / 256, 256, 0, stream>>>(srcs[g], dsts[g], ets[g],
                                                                norms[g], E, dcur, dsrc, det,
                                                                dnorm);
            etsort_kernel<<<(E + 1023) / 1024, 1024, 0, stream>>>(dsrc, det, dnorm, E, ecur,
                                                                  src_s, norm_s, opos_s);
            for (int l = 0; l < 2; ++l) {
                gemm_msg_kernel<<<maxtiles, 512, 0, stream>>>(
                    l ? hb2 : hb + (size_t)g * nnd, Wt + (size_t)l * RREL * DIM * DIM, src_s,
                    opos_s, norm_s, tiles, ntiles, eoff, msg);
                segsum_kernel<<<(NN + 3) / 4, 256, 0, stream>>>(
                    msg, doff, bias + l * DIM, l ? hout : nullptr, l ? nullptr : hb2, NN);
            }
        }
    } else {
        // ---------------- fallback: atomic aggregation path ----------------
        int mt64 = E / 64 + RREL + 1;
        ushort* Wt = (ushort*)alloc((size_t)2 * RREL * DIM * DIM * 2);
        ushort* hb = (ushort*)alloc((size_t)2 * nnd * 2);
        ushort* hb2 = (ushort*)alloc((size_t)nnd * 2);
        float* agg = (float*)alloc((size_t)nnd * 4);
        int* src_s = (int*)alloc((size_t)E * 4);
        int* dst_s = (int*)alloc((size_t)E * 4);
        float* norm_s = (float*)alloc((size_t)E * 4);
        int* hist = (int*)alloc(RREL * 4);
        int* offsets = (int*)alloc((RREL + 1) * 4);
        int* cursor = (int*)alloc(RREL * 4);
        int* ntiles = (int*)alloc(4);
        int2* tiles = (int2*)alloc((size_t)mt64 * 8);

        int fblocks = (nnd / 8 + 255) / 256;
        prep_kernel<<<4096 + 2 * fblocks, 256, 0, stream>>>(coeff, basis, Wt, feats[0], feats[1],
                                                            hb, nnd, fblocks);

        for (int g = 0; g < 2; ++g) {
            float* hout = out + (size_t)5 * P * DIM + (size_t)g * nnd;
            hipMemsetAsync(hist, 0, RREL * 4, stream);
            hist_kernel<<<512, 256, 0, stream>>>(ets[g], E, hist);
            scan_kernel<<<1, 64, 0, stream>>>(hist, offsets, cursor, tiles, ntiles);
            scatter_kernel<<<(E + 255) / 256, 256, 0, stream>>>(srcs[g], dsts[g], ets[g],
                                                                norms[g], E, cursor, src_s,
                                                                dst_s, norm_s);
            for (int l = 0; l < 2; ++l) {
                hipMemsetAsync(agg, 0, (size_t)nnd * 4, stream);
                gemm_scatter_kernel<<<mt64, 256, 0, stream>>>(
                    l ? hb2 : hb + (size_t)g * nnd, Wt + (size_t)l * RREL * DIM * DIM, src_s,
                    dst_s, norm_s, tiles, ntiles, offsets, agg);
                bias_relu_kernel<<<(nnd / 4 + 255) / 256, 256, 0, stream>>>(
                    agg, bias + l * DIM, l ? hout : nullptr, l ? nullptr : hb2, nnd / 4);
            }
        }
    }

    const float* p_h = out + (size_t)5 * P * DIM;
    const float* n_h = p_h + (size_t)NN * DIM;
    long gtotal = (long)5 * P * 32;
    gather_kernel<<<(int)((gtotal + 255) / 256), 256, 0, stream>>>(
        p_h, n_h, w_relation, pg_head, pg_tail, pg_et, ng_head, ng_tail, out, P);
}

// Round 7
// 834.074 us; speedup vs baseline: 1.2648x; 1.1771x over previous
//
#include <hip/hip_runtime.h>

typedef __attribute__((ext_vector_type(8))) short short8;
typedef __attribute__((ext_vector_type(4))) float f32x4;

#define DIM 128
#define RREL 32
#define BB 8            // basis count

__device__ __forceinline__ ushort f2bf(float f) {
    unsigned u = __builtin_bit_cast(unsigned, f);
    u = (u + 0x7FFFu + ((u >> 16) & 1u)) >> 16;
    return (ushort)u;
}
__device__ __forceinline__ float bf2f(unsigned u) {
    return __builtin_bit_cast(float, u << 16);
}

// prep: (a) Bt[l][n][b*128+d] = bf16(basis[l][b][d][n])  (transposed for MFMA B-frag, via LDS)
//       (b) feats -> bf16 for both graphs
__global__ __launch_bounds__(256) void prep_kernel(const float* __restrict__ basis,
                                                   ushort* __restrict__ Bt,
                                                   const float* __restrict__ f0,
                                                   const float* __restrict__ f1,
                                                   ushort* __restrict__ hb, int nnd,
                                                   int fblocks) {
    int bid = blockIdx.x;
    int t = threadIdx.x;
    if (bid < 32) {                       // Bt transpose: 2l x 4n-tiles(32) x 4k-tiles(256)
        __shared__ ushort ld[32][258];
        int l = bid >> 4, sub = bid & 15;
        int n0 = (sub >> 2) * 32, k0 = (sub & 3) * 256;
        const float* bs = basis + (size_t)l * BB * DIM * DIM;
#pragma unroll 4
        for (int it = 0; it < 32; ++it) {
            int idx = it * 256 + t;
            int nn = idx & 31, kd = idx >> 5;        // kd 0..255
            int kg = k0 + kd;
            ld[nn][kd] = f2bf(bs[(size_t)(kg >> 7) * DIM * DIM + (kg & 127) * DIM + n0 + nn]);
        }
        __syncthreads();
        ushort* ob = Bt + (size_t)l * DIM * 1024;
#pragma unroll 4
        for (int it = 0; it < 32; ++it) {
            ob[(size_t)(n0 + it) * 1024 + k0 + t] = ld[it][t];
        }
    } else {                              // feats -> bf16
        int fb = bid - 32;
        int g = fb / fblocks;
        int i = (fb - g * fblocks) * 256 + t;
        int n8 = nnd / 8;
        if (i >= n8) return;
        const float* in = g ? f1 : f0;
        ushort* out = hb + (size_t)g * nnd;
        const float4* p = (const float4*)in + 2 * (size_t)i;
        float4 a = p[0], b = p[1];
        unsigned w0 = f2bf(a.x) | ((unsigned)f2bf(a.y) << 16);
        unsigned w1 = f2bf(a.z) | ((unsigned)f2bf(a.w) << 16);
        unsigned w2 = f2bf(b.x) | ((unsigned)f2bf(b.y) << 16);
        unsigned w3 = f2bf(b.z) | ((unsigned)f2bf(b.w) << 16);
        ((uint4*)out)[i] = make_uint4(w0, w1, w2, w3);
    }
}

__global__ __launch_bounds__(256) void histd_kernel(const int* __restrict__ dst, int E,
                                                    int* __restrict__ dh) {
    for (int i = blockIdx.x * 256 + threadIdx.x; i < E; i += gridDim.x * 256)
        atomicAdd(&dh[dst[i]], 1);
}

__global__ __launch_bounds__(1024) void dscan_kernel(const int* __restrict__ dh, int NN, int E,
                                                     int* __restrict__ doff,
                                                     int* __restrict__ dcur) {
    __shared__ int part[1024];
    int t = threadIdx.x;
    int chunk = (NN + 1023) >> 10;
    int b0 = t * chunk, b1 = b0 + chunk;
    if (b0 > NN) b0 = NN;
    if (b1 > NN) b1 = NN;
    int s = 0;
    for (int i = b0; i < b1; ++i) s += dh[i];
    part[t] = s;
    __syncthreads();
    for (int off = 1; off < 1024; off <<= 1) {
        int v = (t >= off) ? part[t - off] : 0;
        __syncthreads();
        part[t] += v;
        __syncthreads();
    }
    int run = part[t] - s;
    for (int i = b0; i < b1; ++i) {
        doff[i] = run; dcur[i] = run; run += dh[i];
    }
    if (t == 0) doff[NN] = E;
}

// counting-sort edges into dst order; payload packed {src, et, norm_bits}
__global__ __launch_bounds__(256) void dstsort_kernel(const int* __restrict__ src,
                                                      const int* __restrict__ dst,
                                                      const int* __restrict__ et,
                                                      const float* __restrict__ norm, int E,
                                                      int* __restrict__ dcur,
                                                      int4* __restrict__ epack) {
    int i = blockIdx.x * 256 + threadIdx.x;
    if (i >= E) return;
    int p = atomicAdd(&dcur[dst[i]], 1);
    epack[p] = make_int4(src[i], et[i], __builtin_bit_cast(int, norm[i]), 0);
}

// U[d][b*128+dim] = sum_{e->d} coeff[et,b]*norm*h[src][dim]  (one 64-lane wave per dst)
__global__ __launch_bounds__(256) void ustep_kernel(const ushort* __restrict__ hb,
                                                    const float* __restrict__ coeff,
                                                    const int4* __restrict__ epack,
                                                    const int* __restrict__ doff,
                                                    ushort* __restrict__ U, int NN) {
    __shared__ float cb[RREL * BB];
    int t = threadIdx.x;
    if (t < RREL * BB) cb[t] = coeff[t];
    __syncthreads();
    int d = blockIdx.x * 4 + (t >> 6);
    if (d >= NN) return;
    int lane = t & 63;
    int s0 = doff[d], s1 = doff[d + 1];
    float a0[BB], a1[BB];
#pragma unroll
    for (int b = 0; b < BB; ++b) { a0[b] = 0.f; a1[b] = 0.f; }
    int j = s0;
    for (; j + 1 < s1; j += 2) {
        int4 eA = epack[j], eB = epack[j + 1];
        unsigned hA = ((const unsigned*)(hb + (size_t)eA.x * DIM))[lane];
        unsigned hB = ((const unsigned*)(hb + (size_t)eB.x * DIM))[lane];
        float nA = __builtin_bit_cast(float, eA.z), nB = __builtin_bit_cast(float, eB.z);
        float xA = bf2f(hA & 0xffffu), yA = bf2f(hA >> 16);
        float xB = bf2f(hB & 0xffffu), yB = bf2f(hB >> 16);
        const float* cA = cb + eA.y * BB;
        const float* cB = cb + eB.y * BB;
#pragma unroll
        for (int b = 0; b < BB; ++b) {
            float wA = cA[b] * nA, wB = cB[b] * nB;
            a0[b] = fmaf(wA, xA, fmaf(wB, xB, a0[b]));
            a1[b] = fmaf(wA, yA, fmaf(wB, yB, a1[b]));
        }
    }
    if (j < s1) {
        int4 eA = epack[j];
        unsigned hA = ((const unsigned*)(hb + (size_t)eA.x * DIM))[lane];
        float nA = __builtin_bit_cast(float, eA.z);
        float xA = bf2f(hA & 0xffffu), yA = bf2f(hA >> 16);
        const float* cA = cb + eA.y * BB;
#pragma unroll
        for (int b = 0; b < BB; ++b) {
            float wA = cA[b] * nA;
            a0[b] = fmaf(wA, xA, a0[b]);
            a1[b] = fmaf(wA, yA, a1[b]);
        }
    }
    unsigned* Ur = (unsigned*)(U + (size_t)d * 1024);
#pragma unroll
    for (int b = 0; b < BB; ++b)
        Ur[b * 64 + lane] = (unsigned)f2bf(a0[b]) | ((unsigned)f2bf(a1[b]) << 16);
}

// dense GEMM: out[128-row tile] = relu(U[rows][1024] @ Bt^T + bias); A,B dbuf-staged in LDS.
__global__ __launch_bounds__(512) void ugemm_kernel(const ushort* __restrict__ U,
                                                    const ushort* __restrict__ Bt,
                                                    const float* __restrict__ bias,
                                                    float* __restrict__ of32,
                                                    ushort* __restrict__ obf, int NN) {
    __shared__ ushort lds[2][2][DIM][64];   // [buf][A/B][row|n][k-chunk(64)] swizzled
    int t = threadIdx.x;
    int row0 = blockIdx.x * 128;
    int w = t >> 6, l = t & 63;
    int wr = w >> 2, wc = w & 3;            // 2x4 wave grid: 64 rows x 32 cols
    int lr16 = l & 15, lhi = l >> 4;

    int r_row[2], r_sw[2];
    const ushort* aptr[2];
    const ushort* bptr[2];
#pragma unroll
    for (int i = 0; i < 2; ++i) {
        int g = i * 512 + t;
        int row = g >> 3, ci = g & 7;
        r_row[i] = row; r_sw[i] = ci ^ (row & 7);
        int ar = row0 + row; if (ar > NN - 1) ar = NN - 1;
        aptr[i] = U + (size_t)ar * 1024 + ci * 8;
        bptr[i] = Bt + (size_t)row * 1024 + ci * 8;
    }

    f32x4 acc[4][2];
#pragma unroll
    for (int m = 0; m < 4; ++m)
#pragma unroll
        for (int n = 0; n < 2; ++n) acc[m][n] = (f32x4)0.f;

    int4 ra[2], rb[2];
#pragma unroll
    for (int i = 0; i < 2; ++i) { ra[i] = *(const int4*)aptr[i]; rb[i] = *(const int4*)bptr[i]; }
#pragma unroll
    for (int i = 0; i < 2; ++i) {
        ((int4*)&lds[0][0][r_row[i]][0])[r_sw[i]] = ra[i];
        ((int4*)&lds[0][1][r_row[i]][0])[r_sw[i]] = rb[i];
    }
    __syncthreads();

    for (int kk = 0; kk < 16; ++kk) {
        if (kk < 15) {
#pragma unroll
            for (int i = 0; i < 2; ++i) {
                ra[i] = *(const int4*)(aptr[i] + (kk + 1) * 64);
                rb[i] = *(const int4*)(bptr[i] + (kk + 1) * 64);
            }
        }
        const short8* As = (const short8*)&lds[kk & 1][0][0][0];
        const short8* Bs = (const short8*)&lds[kk & 1][1][0][0];
#pragma unroll
        for (int k4 = 0; k4 < 2; ++k4) {
            int kc = k4 * 4 + lhi;
            short8 a[4];
#pragma unroll
            for (int m = 0; m < 4; ++m) {
                int ar = wr * 64 + m * 16 + lr16;
                a[m] = As[ar * 8 + (kc ^ (ar & 7))];
            }
#pragma unroll
            for (int n16 = 0; n16 < 2; ++n16) {
                int n = wc * 32 + n16 * 16 + lr16;
                short8 b = Bs[n * 8 + (kc ^ (n & 7))];
#pragma unroll
                for (int m = 0; m < 4; ++m)
                    acc[m][n16] = __builtin_amdgcn_mfma_f32_16x16x32_bf16(a[m], b, acc[m][n16], 0, 0, 0);
            }
        }
        if (kk < 15) {
            int nb = (kk + 1) & 1;
#pragma unroll
            for (int i = 0; i < 2; ++i) {
                ((int4*)&lds[nb][0][r_row[i]][0])[r_sw[i]] = ra[i];
                ((int4*)&lds[nb][1][r_row[i]][0])[r_sw[i]] = rb[i];
            }
        }
        __syncthreads();
    }

    if (of32) {
#pragma unroll
        for (int m = 0; m < 4; ++m)
#pragma unroll
            for (int j = 0; j < 4; ++j) {
                int row = wr * 64 + m * 16 + lhi * 4 + j;
                if (row0 + row < NN) {
#pragma unroll
                    for (int n16 = 0; n16 < 2; ++n16) {
                        int col = wc * 32 + n16 * 16 + lr16;
                        float v = fmaxf(acc[m][n16][j] + bias[col], 0.f);
                        of32[(size_t)(row0 + row) * DIM + col] = v;
                    }
                }
            }
    } else {
        ushort* Cl = (ushort*)lds;
#pragma unroll
        for (int m = 0; m < 4; ++m)
#pragma unroll
            for (int j = 0; j < 4; ++j) {
                int row = wr * 64 + m * 16 + lhi * 4 + j;
#pragma unroll
                for (int n16 = 0; n16 < 2; ++n16) {
                    int col = wc * 32 + n16 * 16 + lr16;
                    float v = fmaxf(acc[m][n16][j] + bias[col], 0.f);
                    Cl[(row * 128 + col) ^ ((row & 7) << 3)] = f2bf(v);
                }
            }
        __syncthreads();
        const int4* Cv = (const int4*)lds;
#pragma unroll
        for (int i2 = 0; i2 < 4; ++i2) {
            int idx = i2 * 512 + t;
            int row = idx >> 4, ci = idx & 15;
            if (row0 + row < NN) {
                int4 v = Cv[(row * 16 + ci) ^ (row & 7)];
                ((int4*)(obf + (size_t)(row0 + row) * DIM))[ci] = v;
            }
        }
    }
}

__global__ __launch_bounds__(256) void gather_kernel(const float* __restrict__ p_h,
                                                     const float* __restrict__ n_h,
                                                     const float* __restrict__ w_rel,
                                                     const int* __restrict__ pg_head,
                                                     const int* __restrict__ pg_tail,
                                                     const int* __restrict__ pg_et,
                                                     const int* __restrict__ ng_head,
                                                     const int* __restrict__ ng_tail,
                                                     float* __restrict__ out, int P) {
    long tid = (long)blockIdx.x * 256 + threadIdx.x;
    long total = (long)5 * P * 32;
    if (tid >= total) return;
    int c = (int)(tid & 31);
    long rest = tid >> 5;
    int i = (int)(rest % P);
    int which = (int)(rest / P);
    const float* srcp; int row;
    switch (which) {
        case 0: srcp = p_h;   row = pg_head[i]; break;
        case 1: srcp = p_h;   row = pg_tail[i]; break;
        case 2: srcp = w_rel; row = pg_et[i];   break;
        case 3: srcp = n_h;   row = ng_head[i]; break;
        default: srcp = n_h;  row = ng_tail[i]; break;
    }
    float4 v = ((const float4*)(srcp + (size_t)row * DIM))[c];
    ((float4*)out)[((size_t)which * P + i) * 32 + c] = v;
}

extern "C" void kernel_launch(void* const* d_in, const int* in_sizes, int n_in,
                              void* d_out, int out_size, void* d_ws, size_t ws_size,
                              hipStream_t stream) {
    const float* feats[2] = {(const float*)d_in[0], (const float*)d_in[1]};
    const float* w_relation = (const float*)d_in[2];
    const float* coeff = (const float*)d_in[3];
    const float* basis = (const float*)d_in[4];
    const float* bias = (const float*)d_in[5];
    const int* srcs[2] = {(const int*)d_in[6], (const int*)d_in[10]};
    const int* dsts[2] = {(const int*)d_in[7], (const int*)d_in[11]};
    const int* ets[2] = {(const int*)d_in[8], (const int*)d_in[12]};
    const float* norms[2] = {(const float*)d_in[9], (const float*)d_in[13]};
    const int* pg_head = (const int*)d_in[14];
    const int* pg_tail = (const int*)d_in[15];
    const int* pg_et = (const int*)d_in[16];
    const int* ng_head = (const int*)d_in[17];
    const int* ng_tail = (const int*)d_in[18];

    int E = in_sizes[6];
    int P = in_sizes[14];
    int NN = in_sizes[0] / DIM;
    int nnd = NN * DIM;
    float* out = (float*)d_out;

    char* w = (char*)d_ws;
    auto alloc = [&](size_t b) { char* p = w; w += (b + 255) & ~(size_t)255; return p; };

    ushort* Bt = (ushort*)alloc((size_t)2 * DIM * 1024 * 2);     // 512 KB
    ushort* hb = (ushort*)alloc((size_t)2 * nnd * 2);            // feats bf16, both graphs
    ushort* hb2 = (ushort*)alloc((size_t)nnd * 2);               // layer-1 output bf16
    int4* epack = (int4*)alloc((size_t)E * 16);                  // dst-sorted edge payload
    int* dhist = (int*)alloc((size_t)NN * 4);
    int* dcur = (int*)alloc((size_t)NN * 4);
    int* doff = (int*)alloc((size_t)(NN + 1) * 4);
    ushort* U = (ushort*)alloc((size_t)NN * 1024 * 2);           // 61 MB

    int fblocks = (nnd / 8 + 255) / 256;
    prep_kernel<<<32 + 2 * fblocks, 256, 0, stream>>>(basis, Bt, feats[0], feats[1], hb, nnd,
                                                      fblocks);

    int gblocks = (NN + 127) / 128;
    for (int g = 0; g < 2; ++g) {
        float* hout = out + (size_t)5 * P * DIM + (size_t)g * nnd;
        hipMemsetAsync(dhist, 0, (size_t)NN * 4, stream);
        histd_kernel<<<512, 256, 0, stream>>>(dsts[g], E, dhist);
        dscan_kernel<<<1, 1024, 0, stream>>>(dhist, NN, E, doff, dcur);
        dstsort_kernel<<<(E + 255) / 256, 256, 0, stream>>>(srcs[g], dsts[g], ets[g], norms[g],
                                                            E, dcur, epack);
        for (int l = 0; l < 2; ++l) {
            ustep_kernel<<<(NN + 3) / 4, 256, 0, stream>>>(
                l ? hb2 : hb + (size_t)g * nnd, coeff + l * RREL * BB, epack, doff, U, NN);
            ugemm_kernel<<<gblocks, 512, 0, stream>>>(
                U, Bt + (size_t)l * DIM * 1024, bias + l * DIM, l ? hout : nullptr,
                l ? nullptr : hb2, NN);
        }
    }

    const float* p_h = out + (size_t)5 * P * DIM;
    const float* n_h = p_h + (size_t)NN * DIM;
    long gtotal = (long)5 * P * 32;
    gather_kernel<<<(int)((gtotal + 255) / 256), 256, 0, stream>>>(
        p_h, n_h, w_relation, pg_head, pg_tail, pg_et, ng_head, ng_tail, out, P);
}

// Round 8
// 804.367 us; speedup vs baseline: 1.3115x; 1.0369x over previous
//
#include <hip/hip_runtime.h>

typedef __attribute__((ext_vector_type(8))) short short8;
typedef __attribute__((ext_vector_type(4))) float f32x4;

#define DIM 128
#define RREL 32
#define BB 8            // basis count

__device__ __forceinline__ ushort f2bf(float f) {
    unsigned u = __builtin_bit_cast(unsigned, f);
    u = (u + 0x7FFFu + ((u >> 16) & 1u)) >> 16;
    return (ushort)u;
}
__device__ __forceinline__ float bf2f(unsigned u) {
    return __builtin_bit_cast(float, u << 16);
}

// prep: (a) Bt[l][n][b*128+d] = bf16(basis[l][b][d][n])  (B-frag layout, via LDS transpose)
//       (b) feats -> bf16 both graphs   (c) dst histogram both graphs
__global__ __launch_bounds__(256) void prep_kernel(const float* __restrict__ basis,
                                                   ushort* __restrict__ Bt,
                                                   const float* __restrict__ f0,
                                                   const float* __restrict__ f1,
                                                   ushort* __restrict__ hb, int nnd,
                                                   int fblocks,
                                                   const int* __restrict__ dst0,
                                                   const int* __restrict__ dst1,
                                                   int* __restrict__ dh0,
                                                   int* __restrict__ dh1, int E) {
    int bid = blockIdx.x;
    int t = threadIdx.x;
    if (bid < 32) {                       // Bt transpose: 2l x 4n-tiles(32) x 4k-tiles(256)
        __shared__ ushort ld[32][258];
        int l = bid >> 4, sub = bid & 15;
        int n0 = (sub >> 2) * 32, k0 = (sub & 3) * 256;
        const float* bs = basis + (size_t)l * BB * DIM * DIM;
#pragma unroll 4
        for (int it = 0; it < 32; ++it) {
            int idx = it * 256 + t;
            int nn = idx & 31, kd = idx >> 5;
            int kg = k0 + kd;
            ld[nn][kd] = f2bf(bs[(size_t)(kg >> 7) * DIM * DIM + (kg & 127) * DIM + n0 + nn]);
        }
        __syncthreads();
        ushort* ob = Bt + (size_t)l * DIM * 1024;
#pragma unroll 4
        for (int it = 0; it < 32; ++it) {
            ob[(size_t)(n0 + it) * 1024 + k0 + t] = ld[it][t];
        }
    } else if (bid < 32 + 2 * fblocks) {  // feats -> bf16
        int fb = bid - 32;
        int g = fb / fblocks;
        int i = (fb - g * fblocks) * 256 + t;
        int n8 = nnd / 8;
        if (i >= n8) return;
        const float* in = g ? f1 : f0;
        ushort* out = hb + (size_t)g * nnd;
        const float4* p = (const float4*)in + 2 * (size_t)i;
        float4 a = p[0], b = p[1];
        unsigned w0 = f2bf(a.x) | ((unsigned)f2bf(a.y) << 16);
        unsigned w1 = f2bf(a.z) | ((unsigned)f2bf(a.w) << 16);
        unsigned w2 = f2bf(b.x) | ((unsigned)f2bf(b.y) << 16);
        unsigned w3 = f2bf(b.z) | ((unsigned)f2bf(b.w) << 16);
        ((uint4*)out)[i] = make_uint4(w0, w1, w2, w3);
    } else {                              // dst histogram, 512 blocks per graph
        int hbid = bid - (32 + 2 * fblocks);
        int g = hbid >> 9;
        int b = hbid & 511;
        const int* dp = g ? dst1 : dst0;
        int* dh = g ? dh1 : dh0;
        for (int i = b * 256 + t; i < E; i += 512 * 256) atomicAdd(&dh[dp[i]], 1);
    }
}

// per-graph dst prefix scan (blockIdx = graph)
__global__ __launch_bounds__(1024) void dscan2_kernel(const int* __restrict__ dh0,
                                                      const int* __restrict__ dh1, int NN, int E,
                                                      int* __restrict__ doff0,
                                                      int* __restrict__ dcur0,
                                                      int* __restrict__ doff1,
                                                      int* __restrict__ dcur1) {
    __shared__ int part[1024];
    const int* dh = blockIdx.x ? dh1 : dh0;
    int* doff = blockIdx.x ? doff1 : doff0;
    int* dcur = blockIdx.x ? dcur1 : dcur0;
    int t = threadIdx.x;
    int chunk = (NN + 1023) >> 10;
    int b0 = t * chunk, b1 = b0 + chunk;
    if (b0 > NN) b0 = NN;
    if (b1 > NN) b1 = NN;
    int s = 0;
    for (int i = b0; i < b1; ++i) s += dh[i];
    part[t] = s;
    __syncthreads();
    for (int off = 1; off < 1024; off <<= 1) {
        int v = (t >= off) ? part[t - off] : 0;
        __syncthreads();
        part[t] += v;
        __syncthreads();
    }
    int run = part[t] - s;
    for (int i = b0; i < b1; ++i) {
        doff[i] = run; dcur[i] = run; run += dh[i];
    }
    if (t == 0) doff[NN] = E;
}

// counting-sort both graphs' edges into dst order; payload {src, et, norm_bits}
__global__ __launch_bounds__(256) void dstsort2_kernel(
    const int* __restrict__ s0, const int* __restrict__ d0, const int* __restrict__ e0,
    const float* __restrict__ n0, const int* __restrict__ s1, const int* __restrict__ d1,
    const int* __restrict__ e1, const float* __restrict__ n1, int E,
    int* __restrict__ dcur0, int* __restrict__ dcur1,
    int4* __restrict__ ep0, int4* __restrict__ ep1) {
    int i = blockIdx.x * 256 + threadIdx.x;
    const int* src; const int* dst; const int* et; const float* nm;
    int* dcur; int4* ep;
    if (i < E) {
        src = s0; dst = d0; et = e0; nm = n0; dcur = dcur0; ep = ep0;
    } else {
        i -= E;
        if (i >= E) return;
        src = s1; dst = d1; et = e1; nm = n1; dcur = dcur1; ep = ep1;
    }
    int p = atomicAdd(&dcur[dst[i]], 1);
    ep[p] = make_int4(src[i], et[i], __builtin_bit_cast(int, nm[i]), 0);
}

// Fused layer: per 32-dst tile {phase1: U-tile into LDS (A-frag layout); phase2: GEMM vs Bt}.
// out = relu(U @ Bt^T + bias) -> f32 (of32) or bf16 (obf).
__global__ __launch_bounds__(512) void fused_layer_kernel(
    const ushort* __restrict__ hbsrc, const float* __restrict__ coeff,
    const int4* __restrict__ epack, const int* __restrict__ doff,
    const ushort* __restrict__ Bt, const float* __restrict__ bias,
    float* __restrict__ of32, ushort* __restrict__ obf, int NN) {
    __shared__ ushort Ul[32 * 1024];   // 64 KB: [32 rows][1024 k] bf16, 16B-chunk swizzled
    __shared__ ushort Bl[128 * 64];    // 16 KB: staged B chunk; aliases coeff during phase 1

    int t = threadIdx.x;
    int w = t >> 6, lane = t & 63;
    int row0 = blockIdx.x * 32;

    float* cb = (float*)Bl;            // coeff[RREL*BB] lives in Bl during phase 1
    if (t < RREL * BB) cb[t] = coeff[t];
    __syncthreads();

    // ---- phase 1: each wave accumulates 4 dst rows of U into LDS ----
    unsigned* Uw = (unsigned*)Ul;
    int kkb = lane >> 5;               // contributes to kk = b*2 + kkb
    int cisw = (lane >> 2) & 7;        // chunk-in-kk before swizzle
    int lo = lane & 3;                 // word within chunk
#pragma unroll
    for (int i = 0; i < 4; ++i) {
        int row = w * 4 + i;
        int d = row0 + row;
        int s0 = 0, s1 = 0;
        if (d < NN) { s0 = doff[d]; s1 = doff[d + 1]; }
        float a0[BB], a1[BB];
#pragma unroll
        for (int b = 0; b < BB; ++b) { a0[b] = 0.f; a1[b] = 0.f; }
        int j = s0;
        for (; j + 3 < s1; j += 4) {
            int4 eA = epack[j], eB = epack[j + 1], eC = epack[j + 2], eD = epack[j + 3];
            unsigned hA = ((const unsigned*)(hbsrc + (size_t)eA.x * DIM))[lane];
            unsigned hB = ((const unsigned*)(hbsrc + (size_t)eB.x * DIM))[lane];
            unsigned hC = ((const unsigned*)(hbsrc + (size_t)eC.x * DIM))[lane];
            unsigned hD = ((const unsigned*)(hbsrc + (size_t)eD.x * DIM))[lane];
            float nA = __builtin_bit_cast(float, eA.z), nB = __builtin_bit_cast(float, eB.z);
            float nC = __builtin_bit_cast(float, eC.z), nD = __builtin_bit_cast(float, eD.z);
            float xA = bf2f(hA & 0xffffu), yA = bf2f(hA >> 16);
            float xB = bf2f(hB & 0xffffu), yB = bf2f(hB >> 16);
            float xC = bf2f(hC & 0xffffu), yC = bf2f(hC >> 16);
            float xD = bf2f(hD & 0xffffu), yD = bf2f(hD >> 16);
            const float* cA = cb + (eA.y << 3);
            const float* cB = cb + (eB.y << 3);
            const float* cC = cb + (eC.y << 3);
            const float* cD = cb + (eD.y << 3);
#pragma unroll
            for (int b = 0; b < BB; ++b) {
                float wA = cA[b] * nA, wB = cB[b] * nB, wC = cC[b] * nC, wD = cD[b] * nD;
                a0[b] = fmaf(wA, xA, fmaf(wB, xB, fmaf(wC, xC, fmaf(wD, xD, a0[b]))));
                a1[b] = fmaf(wA, yA, fmaf(wB, yB, fmaf(wC, yC, fmaf(wD, yD, a1[b]))));
            }
        }
        for (; j < s1; ++j) {
            int4 eA = epack[j];
            unsigned hA = ((const unsigned*)(hbsrc + (size_t)eA.x * DIM))[lane];
            float nA = __builtin_bit_cast(float, eA.z);
            float xA = bf2f(hA & 0xffffu), yA = bf2f(hA >> 16);
            const float* cA = cb + (eA.y << 3);
#pragma unroll
            for (int b = 0; b < BB; ++b) {
                float wA = cA[b] * nA;
                a0[b] = fmaf(wA, xA, a0[b]);
                a1[b] = fmaf(wA, yA, a1[b]);
            }
        }
        // write row to Ul: word (b*64+lane) -> chunk kk=b*2+kkb, ci=cisw^(row&7), word lo
        int sw = cisw ^ (row & 7);
#pragma unroll
        for (int b = 0; b < BB; ++b) {
            int kk = b * 2 + kkb;
            Uw[row * 512 + kk * 32 + sw * 4 + lo] =
                (unsigned)f2bf(a0[b]) | ((unsigned)f2bf(a1[b]) << 16);
        }
    }
    __syncthreads();

    // ---- phase 2: GEMM 32x128 over K=1024, Bt streamed in 64-k chunks ----
    int lr16 = lane & 15, lhi = lane >> 4;
    f32x4 acc0 = (f32x4)0.f, acc1 = (f32x4)0.f;
    int4* BlV = (int4*)Bl;
    const short8* As = (const short8*)Ul;
    const short8* Bs = (const short8*)Bl;
    int bn = w * 16 + lr16;            // this wave's B column
    for (int kk = 0; kk < 16; ++kk) {
#pragma unroll
        for (int i = 0; i < 2; ++i) {  // stage 16 KB B-chunk
            int g = i * 512 + t;
            int n = g >> 3, ci = g & 7;
            BlV[n * 8 + (ci ^ (n & 7))] =
                ((const int4*)(Bt + (size_t)n * 1024 + kk * 64))[ci];
        }
        __syncthreads();
#pragma unroll
        for (int ks = 0; ks < 2; ++ks) {
            int kc = ks * 4 + lhi;
            short8 b = Bs[bn * 8 + (kc ^ (bn & 7))];
            short8 am0 = As[(0 * 16 + lr16) * 128 + kk * 8 + (kc ^ ((0 * 16 + lr16) & 7))];
            short8 am1 = As[(1 * 16 + lr16) * 128 + kk * 8 + (kc ^ ((1 * 16 + lr16) & 7))];
            acc0 = __builtin_amdgcn_mfma_f32_16x16x32_bf16(am0, b, acc0, 0, 0, 0);
            acc1 = __builtin_amdgcn_mfma_f32_16x16x32_bf16(am1, b, acc1, 0, 0, 0);
        }
        __syncthreads();
    }

    // ---- epilogue: bias + relu ----
    float bv = bias[bn];
    if (of32) {
#pragma unroll
        for (int j = 0; j < 4; ++j) {
            int r0 = lhi * 4 + j;
            int r1 = 16 + r0;
            if (row0 + r0 < NN) of32[(size_t)(row0 + r0) * DIM + bn] = fmaxf(acc0[j] + bv, 0.f);
            if (row0 + r1 < NN) of32[(size_t)(row0 + r1) * DIM + bn] = fmaxf(acc1[j] + bv, 0.f);
        }
    } else {
        ushort* Cl = (ushort*)Bl;      // 32x128 bf16 = 8 KB, fits Bl
#pragma unroll
        for (int j = 0; j < 4; ++j) {
            int r0 = lhi * 4 + j;
            int r1 = 16 + r0;
            Cl[(r0 * 128 + bn) ^ ((r0 & 7) << 3)] = f2bf(fmaxf(acc0[j] + bv, 0.f));
            Cl[(r1 * 128 + bn) ^ ((r1 & 7) << 3)] = f2bf(fmaxf(acc1[j] + bv, 0.f));
        }
        __syncthreads();
        const int4* Cv = (const int4*)Bl;
        int row = t >> 4, ci = t & 15;
        if (row0 + row < NN) {
            int4 v = Cv[(row * 16 + ci) ^ (row & 7)];
            ((int4*)(obf + (size_t)(row0 + row) * DIM))[ci] = v;
        }
    }
}

__global__ __launch_bounds__(256) void gather_kernel(const float* __restrict__ p_h,
                                                     const float* __restrict__ n_h,
                                                     const float* __restrict__ w_rel,
                                                     const int* __restrict__ pg_head,
                                                     const int* __restrict__ pg_tail,
                                                     const int* __restrict__ pg_et,
                                                     const int* __restrict__ ng_head,
                                                     const int* __restrict__ ng_tail,
                                                     float* __restrict__ out, int P) {
    long tid = (long)blockIdx.x * 256 + threadIdx.x;
    long total = (long)5 * P * 32;
    if (tid >= total) return;
    int c = (int)(tid & 31);
    long rest = tid >> 5;
    int i = (int)(rest % P);
    int which = (int)(rest / P);
    const float* srcp; int row;
    switch (which) {
        case 0: srcp = p_h;   row = pg_head[i]; break;
        case 1: srcp = p_h;   row = pg_tail[i]; break;
        case 2: srcp = w_rel; row = pg_et[i];   break;
        case 3: srcp = n_h;   row = ng_head[i]; break;
        default: srcp = n_h;  row = ng_tail[i]; break;
    }
    float4 v = ((const float4*)(srcp + (size_t)row * DIM))[c];
    ((float4*)out)[((size_t)which * P + i) * 32 + c] = v;
}

extern "C" void kernel_launch(void* const* d_in, const int* in_sizes, int n_in,
                              void* d_out, int out_size, void* d_ws, size_t ws_size,
                              hipStream_t stream) {
    const float* feats[2] = {(const float*)d_in[0], (const float*)d_in[1]};
    const float* w_relation = (const float*)d_in[2];
    const float* coeff = (const float*)d_in[3];
    const float* basis = (const float*)d_in[4];
    const float* bias = (const float*)d_in[5];
    const int* srcs[2] = {(const int*)d_in[6], (const int*)d_in[10]};
    const int* dsts[2] = {(const int*)d_in[7], (const int*)d_in[11]};
    const int* ets[2] = {(const int*)d_in[8], (const int*)d_in[12]};
    const float* norms[2] = {(const float*)d_in[9], (const float*)d_in[13]};
    const int* pg_head = (const int*)d_in[14];
    const int* pg_tail = (const int*)d_in[15];
    const int* pg_et = (const int*)d_in[16];
    const int* ng_head = (const int*)d_in[17];
    const int* ng_tail = (const int*)d_in[18];

    int E = in_sizes[6];
    int P = in_sizes[14];
    int NN = in_sizes[0] / DIM;
    int nnd = NN * DIM;
    float* out = (float*)d_out;

    char* w = (char*)d_ws;
    auto alloc = [&](size_t b) { char* p = w; w += (b + 255) & ~(size_t)255; return p; };

    ushort* Bt = (ushort*)alloc((size_t)2 * DIM * 1024 * 2);     // 512 KB
    ushort* hb = (ushort*)alloc((size_t)2 * nnd * 2);            // feats bf16, both graphs
    ushort* hb2 = (ushort*)alloc((size_t)nnd * 2);               // layer-1 output bf16
    int4* ep0 = (int4*)alloc((size_t)E * 16);
    int4* ep1 = (int4*)alloc((size_t)E * 16);
    int* dh0 = (int*)alloc((size_t)NN * 4);                      // dh0,dh1 adjacent: one memset
    int* dh1 = (int*)alloc((size_t)NN * 4);
    int* dcur0 = (int*)alloc((size_t)NN * 4);
    int* dcur1 = (int*)alloc((size_t)NN * 4);
    int* doff0 = (int*)alloc((size_t)(NN + 1) * 4);
    int* doff1 = (int*)alloc((size_t)(NN + 1) * 4);

    float* p_h = out + (size_t)5 * P * DIM;
    float* n_h = p_h + (size_t)nnd;

    hipMemsetAsync(dh0, 0, ((char*)dh1 + (size_t)NN * 4) - (char*)dh0, stream);

    int fblocks = (nnd / 8 + 255) / 256;
    prep_kernel<<<32 + 2 * fblocks + 1024, 256, 0, stream>>>(
        basis, Bt, feats[0], feats[1], hb, nnd, fblocks, dsts[0], dsts[1], dh0, dh1, E);

    dscan2_kernel<<<2, 1024, 0, stream>>>(dh0, dh1, NN, E, doff0, dcur0, doff1, dcur1);

    dstsort2_kernel<<<(2 * E + 255) / 256, 256, 0, stream>>>(
        srcs[0], dsts[0], ets[0], norms[0], srcs[1], dsts[1], ets[1], norms[1], E,
        dcur0, dcur1, ep0, ep1);

    int gblocks = (NN + 31) / 32;
    // g0 l0: hb(g0) -> hb2
    fused_layer_kernel<<<gblocks, 512, 0, stream>>>(hb, coeff, ep0, doff0, Bt, bias,
                                                    nullptr, hb2, NN);
    // g0 l1: hb2 -> p_h (f32)
    fused_layer_kernel<<<gblocks, 512, 0, stream>>>(hb2, coeff + RREL * BB, ep0, doff0,
                                                    Bt + (size_t)DIM * 1024, bias + DIM,
                                                    p_h, nullptr, NN);
    // g1 l0: hb(g1) -> hb2
    fused_layer_kernel<<<gblocks, 512, 0, stream>>>(hb + (size_t)nnd, coeff, ep1, doff1, Bt,
                                                    bias, nullptr, hb2, NN);
    // g1 l1: hb2 -> n_h (f32)
    fused_layer_kernel<<<gblocks, 512, 0, stream>>>(hb2, coeff + RREL * BB, ep1, doff1,
                                                    Bt + (size_t)DIM * 1024, bias + DIM,
                                                    n_h, nullptr, NN);

    long gtotal = (long)5 * P * 32;
    gather_kernel<<<(int)((gtotal + 255) / 256), 256, 0, stream>>>(
        p_h, n_h, w_relation, pg_head, pg_tail, pg_et, ng_head, ng_tail, out, P);
}